// Round 7
// baseline (173.598 us; speedup 1.0000x reference)
//
#include <hip/hip_runtime.h>

// out[r,g] = act( sum_{s=start[g]}^{start[g+1]-1} x[r,s]*w[s] + b[g] )
// act(z) = leaky(leaky(z,0.1),0.2) == (z>=0 ? z : 0.02*z)
//
// No LDS, no barriers. 8 lanes per gene, float4 per lane (32 floats/iter >=
// typical segment ~20). w masked at segment edges, reused across ROWS=8 rows.
// NEW (T1): XCD-chunked block swizzle — gene-blocks padded to a multiple of 8;
// XCD k owns a fixed contiguous slab of gene-blocks for ALL row-sweeps, so its
// w slice (~100 KB) and boundary-overlap x lines stay in its own L2, and each
// XCD streams a clean column-slab of x.

#define GROUP 8
#define ROWS  8
#define NT    256
#define GPB   (NT / GROUP)   // genes per block = 32
#define NXCD  8

__global__ void seg_bounds_kernel(const int* __restrict__ gene_ids,
                                  int* __restrict__ start, int S, int G) {
    int s = blockIdx.x * blockDim.x + threadIdx.x;
    if (s >= S) return;
    int c = gene_ids[s];
    if (s == 0) {
        for (int g = 0; g <= c; ++g) start[g] = 0;
    } else {
        int p = gene_ids[s - 1];
        for (int g = p + 1; g <= c; ++g) start[g] = s;
    }
    if (s == S - 1) {
        for (int g = c + 1; g <= G; ++g) start[g] = S;
    }
}

__global__ __launch_bounds__(NT) void
gene_linear_kernel(const float* __restrict__ x,
                   const float* __restrict__ w,
                   const float* __restrict__ b,
                   const int* __restrict__ start,
                   float* __restrict__ out,
                   int S, int G, int B, int GBX) {
    // bijective XCD-chunked decode: blocks dispatched round-robin over XCDs by
    // linear id; give XCD k the contiguous gene-block slab [k*GBX, (k+1)*GBX),
    // iterating genes inner / row-sweeps outer within each XCD.
    const int bid  = blockIdx.x;
    const int xcd  = bid & (NXCD - 1);
    const int slot = bid >> 3;
    const int gb   = xcd * GBX + (slot % GBX);
    const int rb   = slot / GBX;

    const int tid  = threadIdx.x;
    const int lane = tid & (GROUP - 1);
    const int g    = gb * GPB + (tid / GROUP);
    if (g >= G) return;   // padding gene-blocks exit here

    const int r0  = rb * ROWS;
    if (r0 >= B) return;
    const int ss0 = start[g];
    const int ss1 = start[g + 1];
    const int v0  = ss0 >> 2;                 // first float4 slot of the segment

    const float* __restrict__ x0 = x + (size_t)r0 * (size_t)S;

    float acc[ROWS];
#pragma unroll
    for (int rr = 0; rr < ROWS; ++rr) acc[rr] = 0.0f;

    // S % 4 == 0, so any float4 slot with 4v < ss1 (<= S) stays within the row.
    for (int v = v0 + lane; 4 * v < ss1; v += GROUP) {
        const int e = 4 * v;
        float4 wv = *(const float4*)(w + e);
        // zero w outside [ss0, ss1) — only first/last float4 are partial
        if (e < ss0 || e + 4 > ss1) {
            wv.x = (e + 0 >= ss0 && e + 0 < ss1) ? wv.x : 0.0f;
            wv.y = (e + 1 >= ss0 && e + 1 < ss1) ? wv.y : 0.0f;
            wv.z = (e + 2 >= ss0 && e + 2 < ss1) ? wv.z : 0.0f;
            wv.w = (e + 3 >= ss0 && e + 3 < ss1) ? wv.w : 0.0f;
        }
#pragma unroll
        for (int rr = 0; rr < ROWS; ++rr) {
            const float4 xv = *(const float4*)(x0 + (size_t)rr * (size_t)S + e);
            acc[rr] = fmaf(xv.x, wv.x, acc[rr]);
            acc[rr] = fmaf(xv.y, wv.y, acc[rr]);
            acc[rr] = fmaf(xv.z, wv.z, acc[rr]);
            acc[rr] = fmaf(xv.w, wv.w, acc[rr]);
        }
    }

    // reduce across the 8-lane group (xor 1,2,4 stays inside the group)
#pragma unroll
    for (int rr = 0; rr < ROWS; ++rr) {
        float v = acc[rr];
        v += __shfl_xor(v, 1);
        v += __shfl_xor(v, 2);
        v += __shfl_xor(v, 4);
        acc[rr] = v;
    }

    if (lane == 0) {
        const float bias = b[g];
        const int rn = min(ROWS, B - r0);
        for (int rr = 0; rr < rn; ++rr) {
            const float z = acc[rr] + bias;
            out[(size_t)(r0 + rr) * (size_t)G + g] = (z >= 0.0f) ? z : 0.02f * z;
        }
    }
}

extern "C" void kernel_launch(void* const* d_in, const int* in_sizes, int n_in,
                              void* d_out, int out_size, void* d_ws, size_t ws_size,
                              hipStream_t stream) {
    const float* x        = (const float*)d_in[0];
    const float* w        = (const float*)d_in[1];
    const float* b        = (const float*)d_in[2];
    const int*   gene_ids = (const int*)d_in[3];

    const int S = in_sizes[1];
    const int G = in_sizes[2];
    const int B = in_sizes[0] / S;

    float* out = (float*)d_out;
    int* start = (int*)d_ws;  // (G+1) ints

    // 1) segment boundaries from sorted gene_ids
    {
        int threads = 256;
        int blocks = (S + threads - 1) / threads;
        seg_bounds_kernel<<<blocks, threads, 0, stream>>>(gene_ids, start, S, G);
    }

    // 2) fused segment-dot + bias + double-leaky; XCD-chunked swizzled grid
    {
        const int n_gb  = (G + GPB - 1) / GPB;              // 313
        const int n_gbp = ((n_gb + NXCD - 1) / NXCD) * NXCD; // 320 (padded)
        const int GBX   = n_gbp / NXCD;                      // 40 per XCD
        const int n_rb  = (B + ROWS - 1) / ROWS;             // 128
        dim3 block(NT, 1, 1);
        dim3 grid(n_gbp * n_rb, 1, 1);
        gene_linear_kernel<<<grid, block, 0, stream>>>(x, w, b, start, out,
                                                       S, G, B, GBX);
    }
}

// Round 8
// 168.071 us; speedup vs baseline: 1.0329x; 1.0329x over previous
//
#include <hip/hip_runtime.h>

// out[r,g] = act( sum_{s=start[g]}^{start[g+1]-1} x[r,s]*w[s] + b[g] )
// act(z) = leaky(leaky(z,0.1),0.2) == (z>=0 ? z : 0.02*z)
//
// No LDS, no barriers, default block order (R7's XCD swizzle regressed -7%:
// x is single-touch and w is cache-resident, so T1's reuse mechanism absent).
// 8 lanes per gene, float4 per lane (32 floats/iter >= typical segment ~20).
// w masked at segment edges once, reused across ROWS=16 batch rows (16
// independent fma chains; w-load + mask cost and boundary-line re-reads
// amortized 2x vs ROWS=8). Every wave streams independently: TLP hides HBM.

#define GROUP 8
#define ROWS  16
#define NT    256

__global__ void seg_bounds_kernel(const int* __restrict__ gene_ids,
                                  int* __restrict__ start, int S, int G) {
    int s = blockIdx.x * blockDim.x + threadIdx.x;
    if (s >= S) return;
    int c = gene_ids[s];
    if (s == 0) {
        for (int g = 0; g <= c; ++g) start[g] = 0;
    } else {
        int p = gene_ids[s - 1];
        for (int g = p + 1; g <= c; ++g) start[g] = s;
    }
    if (s == S - 1) {
        for (int g = c + 1; g <= G; ++g) start[g] = S;
    }
}

__global__ __launch_bounds__(NT) void
gene_linear_kernel(const float* __restrict__ x,
                   const float* __restrict__ w,
                   const float* __restrict__ b,
                   const int* __restrict__ start,
                   float* __restrict__ out,
                   int S, int G, int B) {
    const int tid  = threadIdx.x;
    const int lane = tid & (GROUP - 1);
    const int g    = blockIdx.x * (NT / GROUP) + (tid / GROUP);
    if (g >= G) return;

    const int r0  = blockIdx.y * ROWS;
    const int ss0 = start[g];
    const int ss1 = start[g + 1];
    const int v0  = ss0 >> 2;                 // first float4 slot of the segment

    const float* __restrict__ x0 = x + (size_t)r0 * (size_t)S;

    float acc[ROWS];
#pragma unroll
    for (int rr = 0; rr < ROWS; ++rr) acc[rr] = 0.0f;

    // S % 4 == 0, so any float4 slot with 4v < ss1 (<= S) stays within the row.
    for (int v = v0 + lane; 4 * v < ss1; v += GROUP) {
        const int e = 4 * v;
        float4 wv = *(const float4*)(w + e);
        // zero w outside [ss0, ss1) — only first/last float4 of the segment
        // are partial; amortized over ROWS rows.
        if (e < ss0 || e + 4 > ss1) {
            wv.x = (e + 0 >= ss0 && e + 0 < ss1) ? wv.x : 0.0f;
            wv.y = (e + 1 >= ss0 && e + 1 < ss1) ? wv.y : 0.0f;
            wv.z = (e + 2 >= ss0 && e + 2 < ss1) ? wv.z : 0.0f;
            wv.w = (e + 3 >= ss0 && e + 3 < ss1) ? wv.w : 0.0f;
        }
#pragma unroll
        for (int rr = 0; rr < ROWS; ++rr) {
            const float4 xv = *(const float4*)(x0 + (size_t)rr * (size_t)S + e);
            acc[rr] = fmaf(xv.x, wv.x, acc[rr]);
            acc[rr] = fmaf(xv.y, wv.y, acc[rr]);
            acc[rr] = fmaf(xv.z, wv.z, acc[rr]);
            acc[rr] = fmaf(xv.w, wv.w, acc[rr]);
        }
    }

    // reduce across the 8-lane group (xor 1,2,4 stays inside the group)
#pragma unroll
    for (int rr = 0; rr < ROWS; ++rr) {
        float v = acc[rr];
        v += __shfl_xor(v, 1);
        v += __shfl_xor(v, 2);
        v += __shfl_xor(v, 4);
        acc[rr] = v;
    }

    if (lane == 0) {
        const float bias = b[g];
        const int rn = min(ROWS, B - r0);
        for (int rr = 0; rr < rn; ++rr) {
            const float z = acc[rr] + bias;
            out[(size_t)(r0 + rr) * (size_t)G + g] = (z >= 0.0f) ? z : 0.02f * z;
        }
    }
}

extern "C" void kernel_launch(void* const* d_in, const int* in_sizes, int n_in,
                              void* d_out, int out_size, void* d_ws, size_t ws_size,
                              hipStream_t stream) {
    const float* x        = (const float*)d_in[0];
    const float* w        = (const float*)d_in[1];
    const float* b        = (const float*)d_in[2];
    const int*   gene_ids = (const int*)d_in[3];

    const int S = in_sizes[1];
    const int G = in_sizes[2];
    const int B = in_sizes[0] / S;

    float* out = (float*)d_out;
    int* start = (int*)d_ws;  // (G+1) ints

    // 1) segment boundaries from sorted gene_ids
    {
        int threads = 256;
        int blocks = (S + threads - 1) / threads;
        seg_bounds_kernel<<<blocks, threads, 0, stream>>>(gene_ids, start, S, G);
    }

    // 2) fused segment-dot + bias + double-leaky; 8 lanes/gene, float4/lane,
    //    16 rows/thread, no LDS, no barriers
    {
        const int genes_per_block = NT / GROUP;  // 32
        dim3 block(NT, 1, 1);
        dim3 grid((G + genes_per_block - 1) / genes_per_block,
                  (B + ROWS - 1) / ROWS, 1);
        gene_linear_kernel<<<grid, block, 0, stream>>>(x, w, b, start, out, S, G, B);
    }
}

// Round 9
// 162.179 us; speedup vs baseline: 1.0704x; 1.0363x over previous
//
#include <hip/hip_runtime.h>

// out[r,g] = act( sum_{s=start[g]}^{start[g+1]-1} x[r,s]*w[s] + b[g] )
// act(z) = leaky(leaky(z,0.1),0.2) == (z>=0 ? z : 0.02*z)
//
// Final structure (best measured: 161.7 us = 84% of 6.3 TB/s copy ceiling):
// No LDS, no barriers, default block order. 8 lanes per gene, float4 per lane
// (32 floats/iter >= typical segment ~20). w masked at segment edges once,
// reused across ROWS=8 batch rows (8 independent fma chains). Every wave
// streams independently: latency hidden purely by TLP.
// Measured-regressing alternatives: LDS staging (+32%), intra-block double
// buffering (+43%), XCD-chunked swizzle (+7%), ROWS=16 (+4%).

#define GROUP 8
#define ROWS  8
#define NT    256

__global__ void seg_bounds_kernel(const int* __restrict__ gene_ids,
                                  int* __restrict__ start, int S, int G) {
    int s = blockIdx.x * blockDim.x + threadIdx.x;
    if (s >= S) return;
    int c = gene_ids[s];
    if (s == 0) {
        for (int g = 0; g <= c; ++g) start[g] = 0;
    } else {
        int p = gene_ids[s - 1];
        for (int g = p + 1; g <= c; ++g) start[g] = s;
    }
    if (s == S - 1) {
        for (int g = c + 1; g <= G; ++g) start[g] = S;
    }
}

__global__ __launch_bounds__(NT) void
gene_linear_kernel(const float* __restrict__ x,
                   const float* __restrict__ w,
                   const float* __restrict__ b,
                   const int* __restrict__ start,
                   float* __restrict__ out,
                   int S, int G, int B) {
    const int tid  = threadIdx.x;
    const int lane = tid & (GROUP - 1);
    const int g    = blockIdx.x * (NT / GROUP) + (tid / GROUP);
    if (g >= G) return;

    const int r0  = blockIdx.y * ROWS;
    const int ss0 = start[g];
    const int ss1 = start[g + 1];
    const int v0  = ss0 >> 2;                 // first float4 slot of the segment

    const float* __restrict__ x0 = x + (size_t)r0 * (size_t)S;

    float acc[ROWS];
#pragma unroll
    for (int rr = 0; rr < ROWS; ++rr) acc[rr] = 0.0f;

    // S % 4 == 0, so any float4 slot with 4v < ss1 (<= S) stays within the row.
    for (int v = v0 + lane; 4 * v < ss1; v += GROUP) {
        const int e = 4 * v;
        float4 wv = *(const float4*)(w + e);
        // zero w outside [ss0, ss1) — only first/last float4 of the segment
        // are partial; amortized over ROWS rows.
        if (e < ss0 || e + 4 > ss1) {
            wv.x = (e + 0 >= ss0 && e + 0 < ss1) ? wv.x : 0.0f;
            wv.y = (e + 1 >= ss0 && e + 1 < ss1) ? wv.y : 0.0f;
            wv.z = (e + 2 >= ss0 && e + 2 < ss1) ? wv.z : 0.0f;
            wv.w = (e + 3 >= ss0 && e + 3 < ss1) ? wv.w : 0.0f;
        }
#pragma unroll
        for (int rr = 0; rr < ROWS; ++rr) {
            const float4 xv = *(const float4*)(x0 + (size_t)rr * (size_t)S + e);
            acc[rr] = fmaf(xv.x, wv.x, acc[rr]);
            acc[rr] = fmaf(xv.y, wv.y, acc[rr]);
            acc[rr] = fmaf(xv.z, wv.z, acc[rr]);
            acc[rr] = fmaf(xv.w, wv.w, acc[rr]);
        }
    }

    // reduce across the 8-lane group (xor 1,2,4 stays inside the group)
#pragma unroll
    for (int rr = 0; rr < ROWS; ++rr) {
        float v = acc[rr];
        v += __shfl_xor(v, 1);
        v += __shfl_xor(v, 2);
        v += __shfl_xor(v, 4);
        acc[rr] = v;
    }

    if (lane == 0) {
        const float bias = b[g];
        const int rn = min(ROWS, B - r0);
        for (int rr = 0; rr < rn; ++rr) {
            const float z = acc[rr] + bias;
            out[(size_t)(r0 + rr) * (size_t)G + g] = (z >= 0.0f) ? z : 0.02f * z;
        }
    }
}

extern "C" void kernel_launch(void* const* d_in, const int* in_sizes, int n_in,
                              void* d_out, int out_size, void* d_ws, size_t ws_size,
                              hipStream_t stream) {
    const float* x        = (const float*)d_in[0];
    const float* w        = (const float*)d_in[1];
    const float* b        = (const float*)d_in[2];
    const int*   gene_ids = (const int*)d_in[3];

    const int S = in_sizes[1];
    const int G = in_sizes[2];
    const int B = in_sizes[0] / S;

    float* out = (float*)d_out;
    int* start = (int*)d_ws;  // (G+1) ints

    // 1) segment boundaries from sorted gene_ids
    {
        int threads = 256;
        int blocks = (S + threads - 1) / threads;
        seg_bounds_kernel<<<blocks, threads, 0, stream>>>(gene_ids, start, S, G);
    }

    // 2) fused segment-dot + bias + double-leaky; 8 lanes/gene, float4/lane,
    //    8 rows/thread, no LDS, no barriers
    {
        const int genes_per_block = NT / GROUP;  // 32
        dim3 block(NT, 1, 1);
        dim3 grid((G + genes_per_block - 1) / genes_per_block,
                  (B + ROWS - 1) / ROWS, 1);
        gene_linear_kernel<<<grid, block, 0, stream>>>(x, w, b, start, out, S, G, B);
    }
}